// Round 9
// baseline (417.428 us; speedup 1.0000x reference)
//
#include <hip/hip_runtime.h>
#include <math.h>

#define EPSV   1e-5f

typedef __attribute__((ext_vector_type(8))) short bf16x8;
typedef __attribute__((ext_vector_type(4))) float f32x4;

__device__ __forceinline__ short f2bf(float f){
    unsigned u = __float_as_uint(f);
    u += 0x7fffu + ((u >> 16) & 1u);
    return (short)(u >> 16);
}
__device__ __forceinline__ f32x4 mfma16(bf16x8 a, bf16x8 b, f32x4 c){
    return __builtin_amdgcn_mfma_f32_16x16x32_bf16(a, b, c, 0, 0, 0);
}
__device__ __forceinline__ bf16x8 ldfrag(const short* base, int row, int kbyte, int rowBytes){
    int byte = row * rowBytes + kbyte;
    byte ^= (row & 7) << 4;
    return *(const bf16x8*)((const char*)base + byte);
}
__device__ __forceinline__ bf16x8 ldfragG(const short* base, int row, int kbyte, int rowBytes){
    return *(const bf16x8*)((const char*)base + (size_t)row * rowBytes + kbyte);
}
__device__ __forceinline__ void stswz(short* base, int row, int col, int rowBytes, short v){
    int byte = row * rowBytes + col * 2;
    byte ^= (row & 7) << 4;
    *(short*)((char*)base + byte) = v;
}

// ---------------------------------------------------------------------------
// one-shot fp32 -> bf16 weight conversion (unchanged).
// fw2p: fw2p[(((grp*128 + c)*4 + lg)*8 + s)] = W2[c][grp*32 + (s>>2)*16 + lg*4 + (s&3)]
// ---------------------------------------------------------------------------
__global__ __launch_bounds__(256) void cvt_all(
    const float* __restrict__ ipw, const float* __restrict__ opw,
    const float* __restrict__ fw1, const float* __restrict__ fw2,
    short* __restrict__ dst)
{
    int i = (blockIdx.x * 256 + threadIdx.x) * 4;
    if (i >= 1179648) return;
    const float* src; int off;
    if (i < 98304)       { src = ipw; off = i; }
    else if (i < 131072) { src = opw; off = i - 98304; }
    else if (i < 655360) { src = fw1; off = i - 131072; }
    else {
        int o  = i - 655360;
        int L  = o >> 18;
        int oo = o & 262143;
        int s0 = oo & 7;
        int lg = (oo >> 3) & 3;
        int c  = (oo >> 5) & 127;
        int grp = oo >> 12;
        int n  = grp * 32 + ((s0 >> 2) << 4) + lg * 4;
        src = fw2; off = L * 262144 + c * 2048 + n;
        float4 v = *(const float4*)(src + off);
        short4 s;
        s.x = f2bf(v.x); s.y = f2bf(v.y); s.z = f2bf(v.z); s.w = f2bf(v.w);
        *(short4*)(dst + i) = s;
        return;
    }
    float4 v = *(const float4*)(src + off);
    short4 s;
    s.x = f2bf(v.x); s.y = f2bf(v.y); s.z = f2bf(v.z); s.w = f2bf(v.w);
    *(short4*)(dst + i) = s;
}

// ---------------------------------------------------------------------------
// GCN branch (unchanged)
// ---------------------------------------------------------------------------
__global__ __launch_bounds__(256) void gcn_all(
    const float* __restrict__ x,
    const float* __restrict__ Wg1, const float* __restrict__ bg1,
    const float* __restrict__ Wg2, const float* __restrict__ bg2,
    float* __restrict__ xgcn)
{
    int tid = threadIdx.x;
    if (blockIdx.x == 18432) {
        __shared__ float xgm[9];
        __shared__ float h1s[64];
        if (tid < 9) {
            float s = 0.f;
            for (int r = 0; r < 9; ++r) {
                const float* xp = x + (r * 9 + tid) * 7;
                #pragma unroll
                for (int f = 0; f < 7; ++f) s += xp[f];
            }
            xgm[tid] = s * (1.f / 63.f);
        }
        __syncthreads();
        if (tid < 64) {
            float acc = bg1[tid];
            #pragma unroll
            for (int j = 0; j < 9; ++j) acc += xgm[j] * Wg1[j * 64 + tid];
            h1s[tid] = fmaxf(acc, 0.f);
        }
        __syncthreads();
        if (tid < 128) {
            float acc = bg2[tid];
            #pragma unroll 8
            for (int c = 0; c < 64; ++c) acc += h1s[c] * Wg2[c * 128 + tid];
            float v = fmaxf(acc, 0.f);
            for (int r = 0; r < 9; ++r) xgcn[r * 128 + tid] = v;
        }
        return;
    }

    __shared__ float xg[2][9];
    __shared__ float h1[2][64];
    int ri = tid >> 7;
    int tr = tid & 127;
    int row = blockIdx.x * 2 + ri;

    if (tr < 9) {
        const float* xp = x + (row * 9 + tr) * 7;
        float s = 0.f;
        #pragma unroll
        for (int f = 0; f < 7; ++f) s += xp[f];
        xg[ri][tr] = s * (1.f / 7.f);
    }
    __syncthreads();
    if (tr < 64) {
        float acc = bg1[tr];
        #pragma unroll
        for (int j = 0; j < 9; ++j) acc += xg[ri][j] * Wg1[j * 64 + tr];
        h1[ri][tr] = fmaxf(acc, 0.f);
    }
    __syncthreads();
    if (row >= 9) {
        float acc = bg2[tr];
        #pragma unroll 8
        for (int c = 0; c < 64; ++c) acc += h1[ri][c] * Wg2[c * 128 + tr];
        xgcn[row * 128 + tr] = fmaxf(acc, 0.f);
    }
}

// ---------------------------------------------------------------------------
// Conv branch (unchanged)
// ---------------------------------------------------------------------------
__global__ __launch_bounds__(256) void conv_branch(
    const float* __restrict__ x,
    const float* __restrict__ w1, const float* __restrict__ cb1,
    const float* __restrict__ w2, const float* __restrict__ cb2,
    const float* __restrict__ bng, const float* __restrict__ bnb,
    const float* __restrict__ bnm, const float* __restrict__ bnv,
    float* __restrict__ sbuf)
{
    __shared__ float xm[7 * 40];
    __shared__ float w1s[64 * 35];
    __shared__ float o1[64 * 38];
    int tid = threadIdx.x;
    int b = blockIdx.x;

    for (int idx = tid; idx < 7 * 40; idx += 256) xm[idx] = 0.f;
    for (int idx = tid; idx < 64 * 38; idx += 256) o1[idx] = 0.f;
    for (int idx = tid; idx < 2240; idx += 256) w1s[idx] = w1[idx];
    __syncthreads();

    const float* xb = x + (size_t)b * 2268;
    for (int idx = tid; idx < 252; idx += 256) {
        int f = idx / 36, l = idx - f * 36;
        float s = 0.f;
        #pragma unroll
        for (int n = 0; n < 9; ++n) s += xb[n * 252 + idx];
        xm[f * 40 + l + 2] = s * (1.f / 9.f);
    }
    __syncthreads();

    {
        int o = tid & 63, lh = tid >> 6;
        int l0 = lh * 9;
        float acc[9];
        float bias = cb1[o];
        #pragma unroll
        for (int r = 0; r < 9; ++r) acc[r] = bias;
        #pragma unroll
        for (int i = 0; i < 7; ++i) {
            #pragma unroll
            for (int k = 0; k < 5; ++k) {
                float w = w1s[o * 35 + i * 5 + k];
                const float* xrow = &xm[i * 40 + l0 + k];
                #pragma unroll
                for (int r = 0; r < 9; ++r) acc[r] += w * xrow[r];
            }
        }
        #pragma unroll
        for (int r = 0; r < 9; ++r) o1[o * 38 + l0 + r + 1] = acc[r];
    }
    __syncthreads();

    {
        int c = tid & 127, lh = tid >> 7;
        int l0 = lh * 18;
        float acc[18];
        #pragma unroll
        for (int r = 0; r < 18; ++r) acc[r] = 0.f;
        const float* w2c = w2 + c * 192;
        for (int i = 0; i < 64; ++i) {
            float wa = w2c[i * 3 + 0], wb = w2c[i * 3 + 1], wc = w2c[i * 3 + 2];
            const float* orow = &o1[i * 38 + l0];
            #pragma unroll
            for (int r = 0; r < 18; ++r)
                acc[r] += wa * orow[r] + wb * orow[r + 1] + wc * orow[r + 2];
        }
        float scale = bng[c] * rsqrtf(bnv[c] + EPSV);
        float shift = bnb[c] - bnm[c] * scale;
        float bias  = cb2[c];
        float* sb = sbuf + ((size_t)b * 36 + l0) * 128 + c;
        #pragma unroll
        for (int r = 0; r < 18; ++r)
            sb[r * 128] = (acc[r] + bias) * scale + shift;
    }
}

// ---------------------------------------------------------------------------
// Attention + out-proj + residual + LN1 (init trimmed: A-row pad garbage only
// affects discarded output rows; Vt contraction pad still zeroed)
// ---------------------------------------------------------------------------
__global__ __launch_bounds__(256, 2) void attn_mfma(
    float* __restrict__ sbuf,
    const short* __restrict__ ipwb, const float* __restrict__ ipb,
    const short* __restrict__ opwb, const float* __restrict__ opb,
    const float* __restrict__ l1g, const float* __restrict__ l1b)
{
    __shared__ short Sb[48 * 128] __attribute__((aligned(16)));
    __shared__ char  U[38912]     __attribute__((aligned(16)));
    __shared__ float scf[36 * 40];
    short* Qb = (short*)U;
    short* Kb = (short*)(U + 6144);
    short* Vt = (short*)(U + 12288);
    short* Pb = (short*)(U + 20480);
    short* Hb = (short*)(U + 26624);

    const int tid  = threadIdx.x;
    const int wid  = tid >> 6;
    const int lane = tid & 63;
    const int lr   = lane & 15;
    const int lg   = lane >> 4;
    const int kbse = lg * 16;

    float* sg = sbuf + (size_t)blockIdx.x * 4608;
    const f32x4 fzero = {0.f, 0.f, 0.f, 0.f};

    for (int idx = tid; idx < 4608; idx += 256) {
        int r = idx >> 7, c = idx & 127;
        stswz(Sb, r, c, 256, f2bf(sg[idx]));
    }
    for (int idx = tid; idx < 1024; idx += 256)   // Vt seq 48..63 (contraction pad)
        stswz(Vt, idx >> 4, 48 + (idx & 15), 128, 0);
    __syncthreads();

    for (int h = 0; h < 2; ++h) {
        {
            f32x4 acc[3][3];
            #pragma unroll
            for (int a = 0; a < 3; ++a)
                #pragma unroll
                for (int m = 0; m < 3; ++m) acc[a][m] = fzero;
            const int wrow0 = h * 64 + wid * 16 + lr;
            #pragma unroll
            for (int ks = 0; ks < 4; ++ks) {
                bf16x8 a0 = ldfrag(Sb,      lr, ks * 64 + kbse, 256);
                bf16x8 a1 = ldfrag(Sb, 16 + lr, ks * 64 + kbse, 256);
                bf16x8 a2 = ldfrag(Sb, 32 + lr, ks * 64 + kbse, 256);
                #pragma unroll
                for (int mat = 0; mat < 3; ++mat) {
                    bf16x8 bf = ldfragG(ipwb, mat * 128 + wrow0, ks * 64 + kbse, 256);
                    acc[mat][0] = mfma16(a0, bf, acc[mat][0]);
                    acc[mat][1] = mfma16(a1, bf, acc[mat][1]);
                    acc[mat][2] = mfma16(a2, bf, acc[mat][2]);
                }
            }
            int col = wid * 16 + lr;
            #pragma unroll
            for (int mat = 0; mat < 3; ++mat) {
                float bias = ipb[mat * 128 + h * 64 + col];
                #pragma unroll
                for (int mt = 0; mt < 3; ++mt) {
                    f32x4 c4 = acc[mat][mt];
                    if (mat == 0) {
                        #pragma unroll
                        for (int j = 0; j < 4; ++j)
                            stswz(Qb, mt * 16 + lg * 4 + j, col, 128, f2bf(c4[j] + bias));
                    } else if (mat == 1) {
                        #pragma unroll
                        for (int j = 0; j < 4; ++j)
                            stswz(Kb, mt * 16 + lg * 4 + j, col, 128, f2bf(c4[j] + bias));
                    } else {
                        int rbase = mt * 16 + lg * 4;
                        short4 s4;
                        s4.x = f2bf(rbase + 0 < 36 ? c4[0] + bias : 0.f);
                        s4.y = f2bf(rbase + 1 < 36 ? c4[1] + bias : 0.f);
                        s4.z = f2bf(rbase + 2 < 36 ? c4[2] + bias : 0.f);
                        s4.w = f2bf(rbase + 3 < 36 ? c4[3] + bias : 0.f);
                        int byte = col * 128 + rbase * 2;
                        byte ^= (col & 7) << 4;
                        *(short4*)((char*)Vt + byte) = s4;
                    }
                }
            }
        }
        __syncthreads();

        for (int t = wid; t < 9; t += 4) {
            int mt = t / 3, nt = t - mt * 3;
            f32x4 acc = fzero;
            #pragma unroll
            for (int ks = 0; ks < 2; ++ks) {
                bf16x8 a = ldfrag(Qb, mt * 16 + lr, ks * 64 + kbse, 128);
                bf16x8 b = ldfrag(Kb, nt * 16 + lr, ks * 64 + kbse, 128);
                acc = mfma16(a, b, acc);
            }
            int col = nt * 16 + lr;
            if (col < 36) {
                #pragma unroll
                for (int j = 0; j < 4; ++j) {
                    int r = mt * 16 + lg * 4 + j;
                    if (r < 36) scf[r * 40 + col] = acc[j] * 0.125f;
                }
            }
        }
        __syncthreads();

        {
            int g = tid >> 2, e = tid & 3;
            if (g < 36) {
                float v[9];
                float mx = -1e30f;
                #pragma unroll
                for (int i = 0; i < 9; ++i) { v[i] = scf[g * 40 + e * 9 + i]; mx = fmaxf(mx, v[i]); }
                mx = fmaxf(mx, __shfl_xor(mx, 1));
                mx = fmaxf(mx, __shfl_xor(mx, 2));
                float ssum = 0.f;
                #pragma unroll
                for (int i = 0; i < 9; ++i) { v[i] = __expf(v[i] - mx); ssum += v[i]; }
                ssum += __shfl_xor(ssum, 1);
                ssum += __shfl_xor(ssum, 2);
                float inv = 1.f / ssum;
                #pragma unroll
                for (int i = 0; i < 9; ++i)
                    stswz(Pb, g, e * 9 + i, 128, f2bf(v[i] * inv));
                #pragma unroll
                for (int i = 0; i < 7; ++i)
                    stswz(Pb, g, 36 + e * 7 + i, 128, 0);
            }
        }
        __syncthreads();

        {
            f32x4 oacc[3] = {fzero, fzero, fzero};
            #pragma unroll
            for (int ks = 0; ks < 2; ++ks) {
                bf16x8 b = ldfrag(Vt, wid * 16 + lr, ks * 64 + kbse, 128);
                #pragma unroll
                for (int mt = 0; mt < 3; ++mt) {
                    bf16x8 a = ldfrag(Pb, mt * 16 + lr, ks * 64 + kbse, 128);
                    oacc[mt] = mfma16(a, b, oacc[mt]);
                }
            }
            int col = h * 64 + wid * 16 + lr;
            #pragma unroll
            for (int mt = 0; mt < 3; ++mt)
                #pragma unroll
                for (int j = 0; j < 4; ++j)
                    stswz(Hb, mt * 16 + lg * 4 + j, col, 256, f2bf(oacc[mt][j]));
        }
        __syncthreads();
    }

    float z[3][2][4];
    {
        f32x4 pacc[3][2];
        #pragma unroll
        for (int m = 0; m < 3; ++m) { pacc[m][0] = fzero; pacc[m][1] = fzero; }
        #pragma unroll
        for (int ks = 0; ks < 4; ++ks) {
            bf16x8 a0 = ldfrag(Hb,      lr, ks * 64 + kbse, 256);
            bf16x8 a1 = ldfrag(Hb, 16 + lr, ks * 64 + kbse, 256);
            bf16x8 a2 = ldfrag(Hb, 32 + lr, ks * 64 + kbse, 256);
            #pragma unroll
            for (int t = 0; t < 2; ++t) {
                bf16x8 b = ldfragG(opwb, (wid * 2 + t) * 16 + lr, ks * 64 + kbse, 256);
                pacc[0][t] = mfma16(a0, b, pacc[0][t]);
                pacc[1][t] = mfma16(a1, b, pacc[1][t]);
                pacc[2][t] = mfma16(a2, b, pacc[2][t]);
            }
        }
        #pragma unroll
        for (int t = 0; t < 2; ++t) {
            int col = (wid * 2 + t) * 16 + lr;
            float bias = opb[col];
            #pragma unroll
            for (int mt = 0; mt < 3; ++mt)
                #pragma unroll
                for (int j = 0; j < 4; ++j) {
                    int r = mt * 16 + lg * 4 + j;
                    z[mt][t][j] = (r < 36) ? pacc[mt][t][j] + bias + sg[r * 128 + col] : 0.f;
                }
        }
    }
    {
        float* part = scf;
        #pragma unroll
        for (int mt = 0; mt < 3; ++mt)
            #pragma unroll
            for (int j = 0; j < 4; ++j) {
                int r = mt * 16 + lg * 4 + j;
                float s  = z[mt][0][j] + z[mt][1][j];
                float ss = z[mt][0][j] * z[mt][0][j] + z[mt][1][j] * z[mt][1][j];
                s  += __shfl_xor(s, 1);  s  += __shfl_xor(s, 2);
                s  += __shfl_xor(s, 4);  s  += __shfl_xor(s, 8);
                ss += __shfl_xor(ss, 1); ss += __shfl_xor(ss, 2);
                ss += __shfl_xor(ss, 4); ss += __shfl_xor(ss, 8);
                if (lr == 0 && r < 36) { part[r * 8 + wid] = s; part[r * 8 + 4 + wid] = ss; }
            }
    }
    __syncthreads();
    {
        const float* part = scf;
        #pragma unroll
        for (int mt = 0; mt < 3; ++mt)
            #pragma unroll
            for (int j = 0; j < 4; ++j) {
                int r = mt * 16 + lg * 4 + j;
                if (r < 36) {
                    float s  = part[r * 8 + 0] + part[r * 8 + 1] + part[r * 8 + 2] + part[r * 8 + 3];
                    float ss = part[r * 8 + 4] + part[r * 8 + 5] + part[r * 8 + 6] + part[r * 8 + 7];
                    float mean = s * (1.f / 128.f);
                    float rstd = rsqrtf(ss * (1.f / 128.f) - mean * mean + EPSV);
                    #pragma unroll
                    for (int t = 0; t < 2; ++t) {
                        int col = (wid * 2 + t) * 16 + lr;
                        float v = (z[mt][t][j] - mean) * rstd * l1g[col] + l1b[col];
                        sg[r * 128 + col] = v;
                    }
                }
            }
    }
}

// ---------------------------------------------------------------------------
// FFN v4: 2 waves x 32 rows (each LDS weight fragment feeds 2 MFMAs),
// double-buffered LDS weight stage, 1 barrier/chunk, all-static indexing.
// M=64/block, grid 576.
// ---------------------------------------------------------------------------
__global__ __launch_bounds__(128, 1) void ffn_v4(
    float* __restrict__ sres,
    const short* __restrict__ fw1b, const float* __restrict__ fb1,
    const short* __restrict__ fw2p, const float* __restrict__ fb2,
    const float* __restrict__ l2g, const float* __restrict__ l2b)
{
    // per chunk (64 neurons): W1 16KB (swizzled rows) + W2 16KB (frag-linear)
    __shared__ short Wbuf[2][16384] __attribute__((aligned(16)));   // 64 KB

    const int tid  = threadIdx.x;
    const int wid  = tid >> 6;            // 0..1
    const int lane = tid & 63;
    const int lr   = lane & 15;
    const int lg   = lane >> 4;
    const size_t row0 = (size_t)blockIdx.x * 64 + wid * 32;
    const f32x4 fzero = {0.f, 0.f, 0.f, 0.f};

    // persistent S fragments: 2 row-subtiles x 4 k-steps
    bf16x8 sfrag[2][4];
    #pragma unroll
    for (int rt = 0; rt < 2; ++rt) {
        const float* sp = sres + (row0 + rt * 16 + lr) * 128;
        #pragma unroll
        for (int ks = 0; ks < 4; ++ks) {
            float4 lo = *(const float4*)(sp + ks * 32 + lg * 8);
            float4 hi = *(const float4*)(sp + ks * 32 + lg * 8 + 4);
            bf16x8 f;
            f[0] = f2bf(lo.x); f[1] = f2bf(lo.y); f[2] = f2bf(lo.z); f[3] = f2bf(lo.w);
            f[4] = f2bf(hi.x); f[5] = f2bf(hi.y); f[6] = f2bf(hi.z); f[7] = f2bf(hi.w);
            sfrag[rt][ks] = f;
        }
    }

    f32x4 facc[2][8];
    #pragma unroll
    for (int rt = 0; rt < 2; ++rt)
        #pragma unroll
        for (int ct = 0; ct < 8; ++ct) facc[rt][ct] = fzero;

    // staging registers: 16 x 16B per thread per chunk (8 W1 + 8 W2)
    bf16x8 g1[8], g2[8];
    #pragma unroll
    for (int i = 0; i < 8; ++i) {
        int fid = tid + 128 * i;
        g1[i] = *(const bf16x8*)((const char*)fw1b + fid * 16);
        g2[i] = *(const bf16x8*)((const char*)fw2p + fid * 16);
    }
    #pragma unroll
    for (int i = 0; i < 8; ++i) {
        int fid = tid + 128 * i;
        int swz = (fid * 16) ^ (((fid >> 4) & 7) << 4);
        *(bf16x8*)((char*)&Wbuf[0][0] + swz)         = g1[i];
        *(bf16x8*)((char*)&Wbuf[0][8192] + fid * 16) = g2[i];
    }

#define FFN_CHUNK(Q, CUR, NXT)                                                    \
    {                                                                             \
        const int q = (Q);                                                        \
        if (q < 31) {                                                             \
            const char* b1p = (const char*)fw1b + (q + 1) * 16384;                \
            const char* b2p = (const char*)fw2p + (q + 1) * 16384;                \
            _Pragma("unroll")                                                     \
            for (int i = 0; i < 8; ++i) {                                         \
                int fid = tid + 128 * i;                                          \
                g1[i] = *(const bf16x8*)(b1p + fid * 16);                         \
                g2[i] = *(const bf16x8*)(b2p + fid * 16);                         \
            }                                                                     \
        }                                                                         \
        __syncthreads();  /* buf[CUR] writes (prev iter) visible */               \
        const short* W1l = &Wbuf[CUR][0];                                         \
        const short* W2l = &Wbuf[CUR][8192];                                      \
        /* FFN1 swapped: A = W1 frag, B = sfrag -> H^T regs (2 row-tiles) */      \
        f32x4 hacc[2][4];                                                         \
        _Pragma("unroll")                                                         \
        for (int rt = 0; rt < 2; ++rt)                                            \
            _Pragma("unroll")                                                     \
            for (int nt = 0; nt < 4; ++nt) hacc[rt][nt] = fzero;                  \
        _Pragma("unroll")                                                         \
        for (int ks = 0; ks < 4; ++ks)                                            \
            _Pragma("unroll")                                                     \
            for (int nt = 0; nt < 4; ++nt) {                                      \
                bf16x8 a = ldfrag(W1l, nt * 16 + lr, ks * 64 + lg * 16, 256);     \
                hacc[0][nt] = mfma16(a, sfrag[0][ks], hacc[0][nt]);               \
                hacc[1][nt] = mfma16(a, sfrag[1][ks], hacc[1][nt]);               \
            }                                                                     \
        /* bias + relu + pack: slot s <-> n = ksn*32 + (s>>2)*16 + lg*4 + (s&3) */\
        bf16x8 hf[2][2];                                                          \
        _Pragma("unroll")                                                         \
        for (int ksn = 0; ksn < 2; ++ksn) {                                       \
            float4 bA = *(const float4*)(fb1 + q * 64 + ksn * 32 + lg * 4);       \
            float4 bB = *(const float4*)(fb1 + q * 64 + ksn * 32 + 16 + lg * 4);  \
            _Pragma("unroll")                                                     \
            for (int rt = 0; rt < 2; ++rt) {                                      \
                bf16x8 h;                                                         \
                h[0] = f2bf(fmaxf(hacc[rt][ksn * 2][0]     + bA.x, 0.f));         \
                h[1] = f2bf(fmaxf(hacc[rt][ksn * 2][1]     + bA.y, 0.f));         \
                h[2] = f2bf(fmaxf(hacc[rt][ksn * 2][2]     + bA.z, 0.f));         \
                h[3] = f2bf(fmaxf(hacc[rt][ksn * 2][3]     + bA.w, 0.f));         \
                h[4] = f2bf(fmaxf(hacc[rt][ksn * 2 + 1][0] + bB.x, 0.f));         \
                h[5] = f2bf(fmaxf(hacc[rt][ksn * 2 + 1][1] + bB.y, 0.f));         \
                h[6] = f2bf(fmaxf(hacc[rt][ksn * 2 + 1][2] + bB.z, 0.f));         \
                h[7] = f2bf(fmaxf(hacc[rt][ksn * 2 + 1][3] + bB.w, 0.f));         \
                hf[rt][ksn] = h;                                                  \
            }                                                                     \
        }                                                                         \
        /* FFN2: A = hf, B = W2 frag (each LDS read feeds 2 MFMAs) */             \
        _Pragma("unroll")                                                         \
        for (int ksn = 0; ksn < 2; ++ksn)                                         \
            _Pragma("unroll")                                                     \
            for (int ct = 0; ct < 8; ++ct) {                                      \
                bf16x8 b2 = *(const bf16x8*)(W2l +                                \
                              ((ksn * 128 + ct * 16 + lr) * 4 + lg) * 8);         \
                facc[0][ct] = mfma16(hf[0][ksn], b2, facc[0][ct]);                \
                facc[1][ct] = mfma16(hf[1][ksn], b2, facc[1][ct]);                \
            }                                                                     \
        if (q < 31) {                                                             \
            char* d1 = (char*)&Wbuf[NXT][0];                                      \
            char* d2 = (char*)&Wbuf[NXT][8192];                                   \
            _Pragma("unroll")                                                     \
            for (int i = 0; i < 8; ++i) {                                         \
                int fid = tid + 128 * i;                                          \
                int swz = (fid * 16) ^ (((fid >> 4) & 7) << 4);                   \
                *(bf16x8*)(d1 + swz)        = g1[i];                              \
                *(bf16x8*)(d2 + fid * 16)   = g2[i];                              \
            }                                                                     \
        }                                                                         \
    }

    #pragma unroll 1
    for (int qq = 0; qq < 16; ++qq) {
        FFN_CHUNK(2 * qq,     0, 1)
        FFN_CHUNK(2 * qq + 1, 1, 0)
    }
#undef FFN_CHUNK

    // epilogue per row-subtile: + b2 + residual, in-wave LN2, write back
    #pragma unroll
    for (int rt = 0; rt < 2; ++rt) {
        const size_t rowb = row0 + rt * 16;
        float zv[8][4];
        #pragma unroll
        for (int ct = 0; ct < 8; ++ct) {
            int c = ct * 16 + lr;
            float b2v = fb2[c];
            #pragma unroll
            for (int j = 0; j < 4; ++j)
                zv[ct][j] = facc[rt][ct][j] + b2v + sres[(rowb + lg * 4 + j) * 128 + c];
        }
        #pragma unroll
        for (int j = 0; j < 4; ++j) {
            float s = 0.f, sq = 0.f;
            #pragma unroll
            for (int ct = 0; ct < 8; ++ct) { s += zv[ct][j]; sq += zv[ct][j] * zv[ct][j]; }
            s  += __shfl_xor(s, 1);  s  += __shfl_xor(s, 2);
            s  += __shfl_xor(s, 4);  s  += __shfl_xor(s, 8);
            sq += __shfl_xor(sq, 1); sq += __shfl_xor(sq, 2);
            sq += __shfl_xor(sq, 4); sq += __shfl_xor(sq, 8);
            float mean = s * (1.f / 128.f);
            float rstd = rsqrtf(sq * (1.f / 128.f) - mean * mean + EPSV);
            float* og = sres + (rowb + lg * 4 + j) * 128;
            #pragma unroll
            for (int ct = 0; ct < 8; ++ct) {
                int c = ct * 16 + lr;
                og[c] = (zv[ct][j] - mean) * rstd * l2g[c] + l2b[c];
            }
        }
    }
}

// ---------------------------------------------------------------------------
// pool + head (unchanged)
// ---------------------------------------------------------------------------
__global__ __launch_bounds__(128) void pool_head(
    const float* __restrict__ sbuf, const float* __restrict__ xgcn,
    const float* __restrict__ aww, const float* __restrict__ awb,
    const float* __restrict__ fcw, const float* __restrict__ fcb,
    float* __restrict__ out)
{
    __shared__ float sl[36][128];
    __shared__ float zz[36];
    __shared__ float p[128];
    int tid = threadIdx.x;
    int b = blockIdx.x;
    const float* sg = sbuf + (size_t)b * 4608;
    const float* gg = xgcn + (size_t)b * 4608;
    for (int idx = tid; idx < 4608; idx += 128)
        sl[0][idx] = sg[idx] + gg[idx];
    __syncthreads();
    if (tid < 36) {
        float acc = awb[0];
        #pragma unroll
        for (int j = 0; j < 128; j += 4) {
            float4 s4 = *(const float4*)&sl[tid][j];
            float4 w4 = *(const float4*)(aww + j);
            acc += s4.x * w4.x + s4.y * w4.y + s4.z * w4.z + s4.w * w4.w;
        }
        zz[tid] = acc;
    }
    __syncthreads();
    if (tid == 0) {
        float m = -1e30f;
        for (int k = 0; k < 36; ++k) m = fmaxf(m, zz[k]);
        float ssum = 0.f;
        for (int k = 0; k < 36; ++k) ssum += __expf(zz[k] - m);
        float inv = 1.f / ssum;
        for (int k = 0; k < 36; ++k) zz[k] = __expf(zz[k] - m) * inv;
    }
    __syncthreads();
    {
        float acc = 0.f;
        for (int l = 0; l < 36; ++l) acc += sl[l][tid] * zz[l];
        p[tid] = acc;
    }
    __syncthreads();
    if (tid == 0) {
        float acc = fcb[0];
        for (int dd = 0; dd < 128; ++dd) acc += p[dd] * fcw[dd];
        out[b] = acc >= 0.f ? acc : 0.1f * acc;
    }
}

// ---------------------------------------------------------------------------
extern "C" void kernel_launch(void* const* d_in, const int* in_sizes, int n_in,
                              void* d_out, int out_size, void* d_ws, size_t ws_size,
                              hipStream_t stream)
{
    const float* x   = (const float*)d_in[0];
    const float* Wg1 = (const float*)d_in[1];
    const float* bg1 = (const float*)d_in[2];
    const float* Wg2 = (const float*)d_in[3];
    const float* bg2 = (const float*)d_in[4];
    const float* c1w = (const float*)d_in[5];
    const float* c1b = (const float*)d_in[6];
    const float* c2w = (const float*)d_in[7];
    const float* c2b = (const float*)d_in[8];
    const float* bng = (const float*)d_in[9];
    const float* bnb = (const float*)d_in[10];
    const float* bnm = (const float*)d_in[11];
    const float* bnv = (const float*)d_in[12];
    const float* ipw = (const float*)d_in[13];
    const float* ipb = (const float*)d_in[14];
    const float* opw = (const float*)d_in[15];
    const float* opb = (const float*)d_in[16];
    const float* l1g = (const float*)d_in[17];
    const float* l1b = (const float*)d_in[18];
    const float* l2g = (const float*)d_in[19];
    const float* l2b = (const float*)d_in[20];
    const float* fw1 = (const float*)d_in[21];
    const float* fb1 = (const float*)d_in[22];
    const float* fw2 = (const float*)d_in[23];
    const float* fb2 = (const float*)d_in[24];
    const float* aww = (const float*)d_in[25];
    const float* awb = (const float*)d_in[26];
    const float* fcw = (const float*)d_in[27];
    const float* fcb = (const float*)d_in[28];
    float* out = (float*)d_out;

    float* sbuf = (float*)d_ws;                       // 1024*36*128 f32
    float* xgcn = sbuf + (size_t)1024 * 36 * 128;     // 1024*36*128 f32
    short* wb   = (short*)(xgcn + (size_t)1024 * 36 * 128);
    short* ipwb = wb;                  // 2*384*128
    short* opwb = wb + 98304;          // 2*128*128
    short* fw1b = wb + 131072;         // 2*2048*128
    short* fw2p = wb + 655360;         // 2*128*2048 (permuted)

    cvt_all<<<1152, 256, 0, stream>>>(ipw, opw, fw1, fw2, wb);
    gcn_all<<<18433, 256, 0, stream>>>(x, Wg1, bg1, Wg2, bg2, xgcn);
    conv_branch<<<1024, 256, 0, stream>>>(x, c1w, c1b, c2w, c2b,
                                          bng, bnb, bnm, bnv, sbuf);
    for (int i = 0; i < 2; ++i) {
        attn_mfma<<<1024, 256, 0, stream>>>(sbuf,
            ipwb + (size_t)i * 49152, ipb + (size_t)i * 384,
            opwb + (size_t)i * 16384, opb + (size_t)i * 128,
            l1g + (size_t)i * 128, l1b + (size_t)i * 128);
        ffn_v4<<<576, 128, 0, stream>>>(sbuf,
            fw1b + (size_t)i * 262144, fb1 + (size_t)i * 2048,
            fw2p + (size_t)i * 262144, fb2 + (size_t)i * 128,
            l2g + (size_t)i * 128, l2b + (size_t)i * 128);
    }
    pool_head<<<1024, 128, 0, stream>>>(sbuf, xgcn, aww, awb, fcw, fcb, out);
}

// Round 10
// 337.007 us; speedup vs baseline: 1.2386x; 1.2386x over previous
//
#include <hip/hip_runtime.h>
#include <math.h>

#define EPSV   1e-5f

typedef __attribute__((ext_vector_type(8))) short bf16x8;
typedef __attribute__((ext_vector_type(4))) float f32x4;

__device__ __forceinline__ short f2bf(float f){
    unsigned u = __float_as_uint(f);
    u += 0x7fffu + ((u >> 16) & 1u);
    return (short)(u >> 16);
}
__device__ __forceinline__ f32x4 mfma16(bf16x8 a, bf16x8 b, f32x4 c){
    return __builtin_amdgcn_mfma_f32_16x16x32_bf16(a, b, c, 0, 0, 0);
}
__device__ __forceinline__ bf16x8 ldfrag(const short* base, int row, int kbyte, int rowBytes){
    int byte = row * rowBytes + kbyte;
    byte ^= (row & 7) << 4;
    return *(const bf16x8*)((const char*)base + byte);
}
__device__ __forceinline__ bf16x8 ldfragG(const short* base, int row, int kbyte, int rowBytes){
    return *(const bf16x8*)((const char*)base + (size_t)row * rowBytes + kbyte);
}
__device__ __forceinline__ void stswz(short* base, int row, int col, int rowBytes, short v){
    int byte = row * rowBytes + col * 2;
    byte ^= (row & 7) << 4;
    *(short*)((char*)base + byte) = v;
}

// ---------------------------------------------------------------------------
// one-shot fp32 -> bf16 weight conversion (unchanged).
// fw2p: fw2p[(((grp*128 + c)*4 + lg)*8 + s)] = W2[c][grp*32 + (s>>2)*16 + lg*4 + (s&3)]
// ---------------------------------------------------------------------------
__global__ __launch_bounds__(256) void cvt_all(
    const float* __restrict__ ipw, const float* __restrict__ opw,
    const float* __restrict__ fw1, const float* __restrict__ fw2,
    short* __restrict__ dst)
{
    int i = (blockIdx.x * 256 + threadIdx.x) * 4;
    if (i >= 1179648) return;
    const float* src; int off;
    if (i < 98304)       { src = ipw; off = i; }
    else if (i < 131072) { src = opw; off = i - 98304; }
    else if (i < 655360) { src = fw1; off = i - 131072; }
    else {
        int o  = i - 655360;
        int L  = o >> 18;
        int oo = o & 262143;
        int s0 = oo & 7;
        int lg = (oo >> 3) & 3;
        int c  = (oo >> 5) & 127;
        int grp = oo >> 12;
        int n  = grp * 32 + ((s0 >> 2) << 4) + lg * 4;
        src = fw2; off = L * 262144 + c * 2048 + n;
        float4 v = *(const float4*)(src + off);
        short4 s;
        s.x = f2bf(v.x); s.y = f2bf(v.y); s.z = f2bf(v.z); s.w = f2bf(v.w);
        *(short4*)(dst + i) = s;
        return;
    }
    float4 v = *(const float4*)(src + off);
    short4 s;
    s.x = f2bf(v.x); s.y = f2bf(v.y); s.z = f2bf(v.z); s.w = f2bf(v.w);
    *(short4*)(dst + i) = s;
}

// ---------------------------------------------------------------------------
// GCN branch (unchanged)
// ---------------------------------------------------------------------------
__global__ __launch_bounds__(256) void gcn_all(
    const float* __restrict__ x,
    const float* __restrict__ Wg1, const float* __restrict__ bg1,
    const float* __restrict__ Wg2, const float* __restrict__ bg2,
    float* __restrict__ xgcn)
{
    int tid = threadIdx.x;
    if (blockIdx.x == 18432) {
        __shared__ float xgm[9];
        __shared__ float h1s[64];
        if (tid < 9) {
            float s = 0.f;
            for (int r = 0; r < 9; ++r) {
                const float* xp = x + (r * 9 + tid) * 7;
                #pragma unroll
                for (int f = 0; f < 7; ++f) s += xp[f];
            }
            xgm[tid] = s * (1.f / 63.f);
        }
        __syncthreads();
        if (tid < 64) {
            float acc = bg1[tid];
            #pragma unroll
            for (int j = 0; j < 9; ++j) acc += xgm[j] * Wg1[j * 64 + tid];
            h1s[tid] = fmaxf(acc, 0.f);
        }
        __syncthreads();
        if (tid < 128) {
            float acc = bg2[tid];
            #pragma unroll 8
            for (int c = 0; c < 64; ++c) acc += h1s[c] * Wg2[c * 128 + tid];
            float v = fmaxf(acc, 0.f);
            for (int r = 0; r < 9; ++r) xgcn[r * 128 + tid] = v;
        }
        return;
    }

    __shared__ float xg[2][9];
    __shared__ float h1[2][64];
    int ri = tid >> 7;
    int tr = tid & 127;
    int row = blockIdx.x * 2 + ri;

    if (tr < 9) {
        const float* xp = x + (row * 9 + tr) * 7;
        float s = 0.f;
        #pragma unroll
        for (int f = 0; f < 7; ++f) s += xp[f];
        xg[ri][tr] = s * (1.f / 7.f);
    }
    __syncthreads();
    if (tr < 64) {
        float acc = bg1[tr];
        #pragma unroll
        for (int j = 0; j < 9; ++j) acc += xg[ri][j] * Wg1[j * 64 + tr];
        h1[ri][tr] = fmaxf(acc, 0.f);
    }
    __syncthreads();
    if (row >= 9) {
        float acc = bg2[tr];
        #pragma unroll 8
        for (int c = 0; c < 64; ++c) acc += h1[ri][c] * Wg2[c * 128 + tr];
        xgcn[row * 128 + tr] = fmaxf(acc, 0.f);
    }
}

// ---------------------------------------------------------------------------
// Conv branch (unchanged)
// ---------------------------------------------------------------------------
__global__ __launch_bounds__(256) void conv_branch(
    const float* __restrict__ x,
    const float* __restrict__ w1, const float* __restrict__ cb1,
    const float* __restrict__ w2, const float* __restrict__ cb2,
    const float* __restrict__ bng, const float* __restrict__ bnb,
    const float* __restrict__ bnm, const float* __restrict__ bnv,
    float* __restrict__ sbuf)
{
    __shared__ float xm[7 * 40];
    __shared__ float w1s[64 * 35];
    __shared__ float o1[64 * 38];
    int tid = threadIdx.x;
    int b = blockIdx.x;

    for (int idx = tid; idx < 7 * 40; idx += 256) xm[idx] = 0.f;
    for (int idx = tid; idx < 64 * 38; idx += 256) o1[idx] = 0.f;
    for (int idx = tid; idx < 2240; idx += 256) w1s[idx] = w1[idx];
    __syncthreads();

    const float* xb = x + (size_t)b * 2268;
    for (int idx = tid; idx < 252; idx += 256) {
        int f = idx / 36, l = idx - f * 36;
        float s = 0.f;
        #pragma unroll
        for (int n = 0; n < 9; ++n) s += xb[n * 252 + idx];
        xm[f * 40 + l + 2] = s * (1.f / 9.f);
    }
    __syncthreads();

    {
        int o = tid & 63, lh = tid >> 6;
        int l0 = lh * 9;
        float acc[9];
        float bias = cb1[o];
        #pragma unroll
        for (int r = 0; r < 9; ++r) acc[r] = bias;
        #pragma unroll
        for (int i = 0; i < 7; ++i) {
            #pragma unroll
            for (int k = 0; k < 5; ++k) {
                float w = w1s[o * 35 + i * 5 + k];
                const float* xrow = &xm[i * 40 + l0 + k];
                #pragma unroll
                for (int r = 0; r < 9; ++r) acc[r] += w * xrow[r];
            }
        }
        #pragma unroll
        for (int r = 0; r < 9; ++r) o1[o * 38 + l0 + r + 1] = acc[r];
    }
    __syncthreads();

    {
        int c = tid & 127, lh = tid >> 7;
        int l0 = lh * 18;
        float acc[18];
        #pragma unroll
        for (int r = 0; r < 18; ++r) acc[r] = 0.f;
        const float* w2c = w2 + c * 192;
        for (int i = 0; i < 64; ++i) {
            float wa = w2c[i * 3 + 0], wb = w2c[i * 3 + 1], wc = w2c[i * 3 + 2];
            const float* orow = &o1[i * 38 + l0];
            #pragma unroll
            for (int r = 0; r < 18; ++r)
                acc[r] += wa * orow[r] + wb * orow[r + 1] + wc * orow[r + 2];
        }
        float scale = bng[c] * rsqrtf(bnv[c] + EPSV);
        float shift = bnb[c] - bnm[c] * scale;
        float bias  = cb2[c];
        float* sb = sbuf + ((size_t)b * 36 + l0) * 128 + c;
        #pragma unroll
        for (int r = 0; r < 18; ++r)
            sb[r * 128] = (acc[r] + bias) * scale + shift;
    }
}

// ---------------------------------------------------------------------------
// Attention + out-proj + residual + LN1 (unchanged from round 9)
// ---------------------------------------------------------------------------
__global__ __launch_bounds__(256, 2) void attn_mfma(
    float* __restrict__ sbuf,
    const short* __restrict__ ipwb, const float* __restrict__ ipb,
    const short* __restrict__ opwb, const float* __restrict__ opb,
    const float* __restrict__ l1g, const float* __restrict__ l1b)
{
    __shared__ short Sb[48 * 128] __attribute__((aligned(16)));
    __shared__ char  U[38912]     __attribute__((aligned(16)));
    __shared__ float scf[36 * 40];
    short* Qb = (short*)U;
    short* Kb = (short*)(U + 6144);
    short* Vt = (short*)(U + 12288);
    short* Pb = (short*)(U + 20480);
    short* Hb = (short*)(U + 26624);

    const int tid  = threadIdx.x;
    const int wid  = tid >> 6;
    const int lane = tid & 63;
    const int lr   = lane & 15;
    const int lg   = lane >> 4;
    const int kbse = lg * 16;

    float* sg = sbuf + (size_t)blockIdx.x * 4608;
    const f32x4 fzero = {0.f, 0.f, 0.f, 0.f};

    for (int idx = tid; idx < 4608; idx += 256) {
        int r = idx >> 7, c = idx & 127;
        stswz(Sb, r, c, 256, f2bf(sg[idx]));
    }
    for (int idx = tid; idx < 1024; idx += 256)   // Vt seq 48..63 (contraction pad)
        stswz(Vt, idx >> 4, 48 + (idx & 15), 128, 0);
    __syncthreads();

    for (int h = 0; h < 2; ++h) {
        {
            f32x4 acc[3][3];
            #pragma unroll
            for (int a = 0; a < 3; ++a)
                #pragma unroll
                for (int m = 0; m < 3; ++m) acc[a][m] = fzero;
            const int wrow0 = h * 64 + wid * 16 + lr;
            #pragma unroll
            for (int ks = 0; ks < 4; ++ks) {
                bf16x8 a0 = ldfrag(Sb,      lr, ks * 64 + kbse, 256);
                bf16x8 a1 = ldfrag(Sb, 16 + lr, ks * 64 + kbse, 256);
                bf16x8 a2 = ldfrag(Sb, 32 + lr, ks * 64 + kbse, 256);
                #pragma unroll
                for (int mat = 0; mat < 3; ++mat) {
                    bf16x8 bf = ldfragG(ipwb, mat * 128 + wrow0, ks * 64 + kbse, 256);
                    acc[mat][0] = mfma16(a0, bf, acc[mat][0]);
                    acc[mat][1] = mfma16(a1, bf, acc[mat][1]);
                    acc[mat][2] = mfma16(a2, bf, acc[mat][2]);
                }
            }
            int col = wid * 16 + lr;
            #pragma unroll
            for (int mat = 0; mat < 3; ++mat) {
                float bias = ipb[mat * 128 + h * 64 + col];
                #pragma unroll
                for (int mt = 0; mt < 3; ++mt) {
                    f32x4 c4 = acc[mat][mt];
                    if (mat == 0) {
                        #pragma unroll
                        for (int j = 0; j < 4; ++j)
                            stswz(Qb, mt * 16 + lg * 4 + j, col, 128, f2bf(c4[j] + bias));
                    } else if (mat == 1) {
                        #pragma unroll
                        for (int j = 0; j < 4; ++j)
                            stswz(Kb, mt * 16 + lg * 4 + j, col, 128, f2bf(c4[j] + bias));
                    } else {
                        int rbase = mt * 16 + lg * 4;
                        short4 s4;
                        s4.x = f2bf(rbase + 0 < 36 ? c4[0] + bias : 0.f);
                        s4.y = f2bf(rbase + 1 < 36 ? c4[1] + bias : 0.f);
                        s4.z = f2bf(rbase + 2 < 36 ? c4[2] + bias : 0.f);
                        s4.w = f2bf(rbase + 3 < 36 ? c4[3] + bias : 0.f);
                        int byte = col * 128 + rbase * 2;
                        byte ^= (col & 7) << 4;
                        *(short4*)((char*)Vt + byte) = s4;
                    }
                }
            }
        }
        __syncthreads();

        for (int t = wid; t < 9; t += 4) {
            int mt = t / 3, nt = t - mt * 3;
            f32x4 acc = fzero;
            #pragma unroll
            for (int ks = 0; ks < 2; ++ks) {
                bf16x8 a = ldfrag(Qb, mt * 16 + lr, ks * 64 + kbse, 128);
                bf16x8 b = ldfrag(Kb, nt * 16 + lr, ks * 64 + kbse, 128);
                acc = mfma16(a, b, acc);
            }
            int col = nt * 16 + lr;
            if (col < 36) {
                #pragma unroll
                for (int j = 0; j < 4; ++j) {
                    int r = mt * 16 + lg * 4 + j;
                    if (r < 36) scf[r * 40 + col] = acc[j] * 0.125f;
                }
            }
        }
        __syncthreads();

        {
            int g = tid >> 2, e = tid & 3;
            if (g < 36) {
                float v[9];
                float mx = -1e30f;
                #pragma unroll
                for (int i = 0; i < 9; ++i) { v[i] = scf[g * 40 + e * 9 + i]; mx = fmaxf(mx, v[i]); }
                mx = fmaxf(mx, __shfl_xor(mx, 1));
                mx = fmaxf(mx, __shfl_xor(mx, 2));
                float ssum = 0.f;
                #pragma unroll
                for (int i = 0; i < 9; ++i) { v[i] = __expf(v[i] - mx); ssum += v[i]; }
                ssum += __shfl_xor(ssum, 1);
                ssum += __shfl_xor(ssum, 2);
                float inv = 1.f / ssum;
                #pragma unroll
                for (int i = 0; i < 9; ++i)
                    stswz(Pb, g, e * 9 + i, 128, f2bf(v[i] * inv));
                #pragma unroll
                for (int i = 0; i < 7; ++i)
                    stswz(Pb, g, 36 + e * 7 + i, 128, 0);
            }
        }
        __syncthreads();

        {
            f32x4 oacc[3] = {fzero, fzero, fzero};
            #pragma unroll
            for (int ks = 0; ks < 2; ++ks) {
                bf16x8 b = ldfrag(Vt, wid * 16 + lr, ks * 64 + kbse, 128);
                #pragma unroll
                for (int mt = 0; mt < 3; ++mt) {
                    bf16x8 a = ldfrag(Pb, mt * 16 + lr, ks * 64 + kbse, 128);
                    oacc[mt] = mfma16(a, b, oacc[mt]);
                }
            }
            int col = h * 64 + wid * 16 + lr;
            #pragma unroll
            for (int mt = 0; mt < 3; ++mt)
                #pragma unroll
                for (int j = 0; j < 4; ++j)
                    stswz(Hb, mt * 16 + lg * 4 + j, col, 256, f2bf(oacc[mt][j]));
        }
        __syncthreads();
    }

    float z[3][2][4];
    {
        f32x4 pacc[3][2];
        #pragma unroll
        for (int m = 0; m < 3; ++m) { pacc[m][0] = fzero; pacc[m][1] = fzero; }
        #pragma unroll
        for (int ks = 0; ks < 4; ++ks) {
            bf16x8 a0 = ldfrag(Hb,      lr, ks * 64 + kbse, 256);
            bf16x8 a1 = ldfrag(Hb, 16 + lr, ks * 64 + kbse, 256);
            bf16x8 a2 = ldfrag(Hb, 32 + lr, ks * 64 + kbse, 256);
            #pragma unroll
            for (int t = 0; t < 2; ++t) {
                bf16x8 b = ldfragG(opwb, (wid * 2 + t) * 16 + lr, ks * 64 + kbse, 256);
                pacc[0][t] = mfma16(a0, b, pacc[0][t]);
                pacc[1][t] = mfma16(a1, b, pacc[1][t]);
                pacc[2][t] = mfma16(a2, b, pacc[2][t]);
            }
        }
        #pragma unroll
        for (int t = 0; t < 2; ++t) {
            int col = (wid * 2 + t) * 16 + lr;
            float bias = opb[col];
            #pragma unroll
            for (int mt = 0; mt < 3; ++mt)
                #pragma unroll
                for (int j = 0; j < 4; ++j) {
                    int r = mt * 16 + lg * 4 + j;
                    z[mt][t][j] = (r < 36) ? pacc[mt][t][j] + bias + sg[r * 128 + col] : 0.f;
                }
        }
    }
    {
        float* part = scf;
        #pragma unroll
        for (int mt = 0; mt < 3; ++mt)
            #pragma unroll
            for (int j = 0; j < 4; ++j) {
                int r = mt * 16 + lg * 4 + j;
                float s  = z[mt][0][j] + z[mt][1][j];
                float ss = z[mt][0][j] * z[mt][0][j] + z[mt][1][j] * z[mt][1][j];
                s  += __shfl_xor(s, 1);  s  += __shfl_xor(s, 2);
                s  += __shfl_xor(s, 4);  s  += __shfl_xor(s, 8);
                ss += __shfl_xor(ss, 1); ss += __shfl_xor(ss, 2);
                ss += __shfl_xor(ss, 4); ss += __shfl_xor(ss, 8);
                if (lr == 0 && r < 36) { part[r * 8 + wid] = s; part[r * 8 + 4 + wid] = ss; }
            }
    }
    __syncthreads();
    {
        const float* part = scf;
        #pragma unroll
        for (int mt = 0; mt < 3; ++mt)
            #pragma unroll
            for (int j = 0; j < 4; ++j) {
                int r = mt * 16 + lg * 4 + j;
                if (r < 36) {
                    float s  = part[r * 8 + 0] + part[r * 8 + 1] + part[r * 8 + 2] + part[r * 8 + 3];
                    float ss = part[r * 8 + 4] + part[r * 8 + 5] + part[r * 8 + 6] + part[r * 8 + 7];
                    float mean = s * (1.f / 128.f);
                    float rstd = rsqrtf(ss * (1.f / 128.f) - mean * mean + EPSV);
                    #pragma unroll
                    for (int t = 0; t < 2; ++t) {
                        int col = (wid * 2 + t) * 16 + lr;
                        float v = (z[mt][t][j] - mean) * rstd * l1g[col] + l1b[col];
                        sg[r * 128 + col] = v;
                    }
                }
            }
    }
}

// ---------------------------------------------------------------------------
// FFN v5: round-8 structure (4 waves x 16 rows, LDS-staged shared weights,
// 1 barrier/chunk, static indexing) with chunk=32 neurons -> 32KB LDS ->
// 4 blocks/CU (~16 waves/CU). M=64/block, grid 576, 64 chunks.
// ---------------------------------------------------------------------------
__global__ __launch_bounds__(256, 4) void ffn_v5(
    float* __restrict__ sres,
    const short* __restrict__ fw1b, const float* __restrict__ fb1,
    const short* __restrict__ fw2p, const float* __restrict__ fb2,
    const float* __restrict__ l2g, const float* __restrict__ l2b)
{
    // per chunk (32 neurons): W1 8KB (swizzled rows) + W2 8KB (frag-linear)
    __shared__ short Wbuf[2][8192] __attribute__((aligned(16)));   // 32 KB

    const int tid  = threadIdx.x;
    const int wid  = tid >> 6;
    const int lane = tid & 63;
    const int lr   = lane & 15;
    const int lg   = lane >> 4;
    const size_t row0 = (size_t)blockIdx.x * 64 + wid * 16;   // wave's rows
    const f32x4 fzero = {0.f, 0.f, 0.f, 0.f};

    // persistent S fragments (B-operand of swapped FFN1)
    bf16x8 sfrag[4];
    {
        const float* sp = sres + (row0 + lr) * 128;
        #pragma unroll
        for (int ks = 0; ks < 4; ++ks) {
            float4 lo = *(const float4*)(sp + ks * 32 + lg * 8);
            float4 hi = *(const float4*)(sp + ks * 32 + lg * 8 + 4);
            bf16x8 f;
            f[0] = f2bf(lo.x); f[1] = f2bf(lo.y); f[2] = f2bf(lo.z); f[3] = f2bf(lo.w);
            f[4] = f2bf(hi.x); f[5] = f2bf(hi.y); f[6] = f2bf(hi.z); f[7] = f2bf(hi.w);
            sfrag[ks] = f;
        }
    }

    f32x4 facc[8];
    #pragma unroll
    for (int ct = 0; ct < 8; ++ct) facc[ct] = fzero;

    // staging: per chunk 16KB total -> 2x16B W1 + 2x16B W2 per thread
    bf16x8 g1[2], g2[2];
    #pragma unroll
    for (int i = 0; i < 2; ++i) {
        int fid = tid + 256 * i;
        g1[i] = *(const bf16x8*)((const char*)fw1b + fid * 16);
        g2[i] = *(const bf16x8*)((const char*)fw2p + fid * 16);
    }
    #pragma unroll
    for (int i = 0; i < 2; ++i) {
        int fid = tid + 256 * i;
        int swz = (fid * 16) ^ (((fid >> 4) & 7) << 4);
        *(bf16x8*)((char*)&Wbuf[0][0] + swz)         = g1[i];
        *(bf16x8*)((char*)&Wbuf[0][4096] + fid * 16) = g2[i];
    }

#define FFN_CHUNK(Q, CUR, NXT)                                                    \
    {                                                                             \
        const int q = (Q);                                                        \
        if (q < 63) {                                                             \
            const char* b1p = (const char*)fw1b + (q + 1) * 8192;                 \
            const char* b2p = (const char*)fw2p + (q + 1) * 8192;                 \
            _Pragma("unroll")                                                     \
            for (int i = 0; i < 2; ++i) {                                         \
                int fid = tid + 256 * i;                                          \
                g1[i] = *(const bf16x8*)(b1p + fid * 16);                         \
                g2[i] = *(const bf16x8*)(b2p + fid * 16);                         \
            }                                                                     \
        }                                                                         \
        __syncthreads();  /* buf[CUR] writes (prev iter) visible */               \
        const short* W1l = &Wbuf[CUR][0];                                         \
        const short* W2l = &Wbuf[CUR][4096];                                      \
        /* FFN1 swapped: A = W1 frag (LDS), B = sfrag -> H^T in regs */           \
        f32x4 hacc[2];                                                            \
        hacc[0] = fzero; hacc[1] = fzero;                                         \
        _Pragma("unroll")                                                         \
        for (int ks = 0; ks < 4; ++ks) {                                          \
            bf16x8 a0 = ldfrag(W1l,      lr, ks * 64 + lg * 16, 256);             \
            bf16x8 a1 = ldfrag(W1l, 16 + lr, ks * 64 + lg * 16, 256);             \
            hacc[0] = mfma16(a0, sfrag[ks], hacc[0]);                             \
            hacc[1] = mfma16(a1, sfrag[ks], hacc[1]);                             \
        }                                                                         \
        /* bias + relu + pack: slot s <-> n = (s>>2)*16 + lg*4 + (s&3) */         \
        float4 bA = *(const float4*)(fb1 + q * 32 + lg * 4);                      \
        float4 bB = *(const float4*)(fb1 + q * 32 + 16 + lg * 4);                 \
        bf16x8 hf;                                                                \
        hf[0] = f2bf(fmaxf(hacc[0][0] + bA.x, 0.f));                              \
        hf[1] = f2bf(fmaxf(hacc[0][1] + bA.y, 0.f));                              \
        hf[2] = f2bf(fmaxf(hacc[0][2] + bA.z, 0.f));                              \
        hf[3] = f2bf(fmaxf(hacc[0][3] + bA.w, 0.f));                              \
        hf[4] = f2bf(fmaxf(hacc[1][0] + bB.x, 0.f));                              \
        hf[5] = f2bf(fmaxf(hacc[1][1] + bB.y, 0.f));                              \
        hf[6] = f2bf(fmaxf(hacc[1][2] + bB.z, 0.f));                              \
        hf[7] = f2bf(fmaxf(hacc[1][3] + bB.w, 0.f));                              \
        /* FFN2: A = hf (regs), B = W2 frag (LDS, frag-linear = conflict-free) */ \
        _Pragma("unroll")                                                         \
        for (int ct = 0; ct < 8; ++ct) {                                          \
            bf16x8 b2 = *(const bf16x8*)(W2l + ((ct * 16 + lr) * 4 + lg) * 8);    \
            facc[ct] = mfma16(hf, b2, facc[ct]);                                  \
        }                                                                         \
        if (q < 63) {                                                             \
            char* d1 = (char*)&Wbuf[NXT][0];                                      \
            char* d2 = (char*)&Wbuf[NXT][4096];                                   \
            _Pragma("unroll")                                                     \
            for (int i = 0; i < 2; ++i) {                                         \
                int fid = tid + 256 * i;                                          \
                int swz = (fid * 16) ^ (((fid >> 4) & 7) << 4);                   \
                *(bf16x8*)(d1 + swz)        = g1[i];                              \
                *(bf16x8*)(d2 + fid * 16)   = g2[i];                              \
            }                                                                     \
        }                                                                         \
    }

    #pragma unroll 1
    for (int qq = 0; qq < 32; ++qq) {
        FFN_CHUNK(2 * qq,     0, 1)
        FFN_CHUNK(2 * qq + 1, 1, 0)
    }
#undef FFN_CHUNK

    // epilogue: + b2 + residual, in-wave LN2, write back
    // facc[ct] lane(lr,lg) reg j = O[row0 + lg*4 + j][ct*16 + lr]
    float zv[8][4];
    #pragma unroll
    for (int ct = 0; ct < 8; ++ct) {
        int c = ct * 16 + lr;
        float b2v = fb2[c];
        #pragma unroll
        for (int j = 0; j < 4; ++j)
            zv[ct][j] = facc[ct][j] + b2v + sres[(row0 + lg * 4 + j) * 128 + c];
    }
    #pragma unroll
    for (int j = 0; j < 4; ++j) {
        float s = 0.f, sq = 0.f;
        #pragma unroll
        for (int ct = 0; ct < 8; ++ct) { s += zv[ct][j]; sq += zv[ct][j] * zv[ct][j]; }
        s  += __shfl_xor(s, 1);  s  += __shfl_xor(s, 2);
        s  += __shfl_xor(s, 4);  s  += __shfl_xor(s, 8);
        sq += __shfl_xor(sq, 1); sq += __shfl_xor(sq, 2);
        sq += __shfl_xor(sq, 4); sq += __shfl_xor(sq, 8);
        float mean = s * (1.f / 128.f);
        float rstd = rsqrtf(sq * (1.f / 128.f) - mean * mean + EPSV);
        float* og = sres + (row0 + lg * 4 + j) * 128;
        #pragma unroll
        for (int ct = 0; ct < 8; ++ct) {
            int c = ct * 16 + lr;
            og[c] = (zv[ct][j] - mean) * rstd * l2g[c] + l2b[c];
        }
    }
}

// ---------------------------------------------------------------------------
// pool + head (unchanged)
// ---------------------------------------------------------------------------
__global__ __launch_bounds__(128) void pool_head(
    const float* __restrict__ sbuf, const float* __restrict__ xgcn,
    const float* __restrict__ aww, const float* __restrict__ awb,
    const float* __restrict__ fcw, const float* __restrict__ fcb,
    float* __restrict__ out)
{
    __shared__ float sl[36][128];
    __shared__ float zz[36];
    __shared__ float p[128];
    int tid = threadIdx.x;
    int b = blockIdx.x;
    const float* sg = sbuf + (size_t)b * 4608;
    const float* gg = xgcn + (size_t)b * 4608;
    for (int idx = tid; idx < 4608; idx += 128)
        sl[0][idx] = sg[idx] + gg[idx];
    __syncthreads();
    if (tid < 36) {
        float acc = awb[0];
        #pragma unroll
        for (int j = 0; j < 128; j += 4) {
            float4 s4 = *(const float4*)&sl[tid][j];
            float4 w4 = *(const float4*)(aww + j);
            acc += s4.x * w4.x + s4.y * w4.y + s4.z * w4.z + s4.w * w4.w;
        }
        zz[tid] = acc;
    }
    __syncthreads();
    if (tid == 0) {
        float m = -1e30f;
        for (int k = 0; k < 36; ++k) m = fmaxf(m, zz[k]);
        float ssum = 0.f;
        for (int k = 0; k < 36; ++k) ssum += __expf(zz[k] - m);
        float inv = 1.f / ssum;
        for (int k = 0; k < 36; ++k) zz[k] = __expf(zz[k] - m) * inv;
    }
    __syncthreads();
    {
        float acc = 0.f;
        for (int l = 0; l < 36; ++l) acc += sl[l][tid] * zz[l];
        p[tid] = acc;
    }
    __syncthreads();
    if (tid == 0) {
        float acc = fcb[0];
        for (int dd = 0; dd < 128; ++dd) acc += p[dd] * fcw[dd];
        out[b] = acc >= 0.f ? acc : 0.1f * acc;
    }
}

// ---------------------------------------------------------------------------
extern "C" void kernel_launch(void* const* d_in, const int* in_sizes, int n_in,
                              void* d_out, int out_size, void* d_ws, size_t ws_size,
                              hipStream_t stream)
{
    const float* x   = (const float*)d_in[0];
    const float* Wg1 = (const float*)d_in[1];
    const float* bg1 = (const float*)d_in[2];
    const float* Wg2 = (const float*)d_in[3];
    const float* bg2 = (const float*)d_in[4];
    const float* c1w = (const float*)d_in[5];
    const float* c1b = (const float*)d_in[6];
    const float* c2w = (const float*)d_in[7];
    const float* c2b = (const float*)d_in[8];
    const float* bng = (const float*)d_in[9];
    const float* bnb = (const float*)d_in[10];
    const float* bnm = (const float*)d_in[11];
    const float* bnv = (const float*)d_in[12];
    const float* ipw = (const float*)d_in[13];
    const float* ipb = (const float*)d_in[14];
    const float* opw = (const float*)d_in[15];
    const float* opb = (const float*)d_in[16];
    const float* l1g = (const float*)d_in[17];
    const float* l1b = (const float*)d_in[18];
    const float* l2g = (const float*)d_in[19];
    const float* l2b = (const float*)d_in[20];
    const float* fw1 = (const float*)d_in[21];
    const float* fb1 = (const float*)d_in[22];
    const float* fw2 = (const float*)d_in[23];
    const float* fb2 = (const float*)d_in[24];
    const float* aww = (const float*)d_in[25];
    const float* awb = (const float*)d_in[26];
    const float* fcw = (const float*)d_in[27];
    const float* fcb = (const float*)d_in[28];
    float* out = (float*)d_out;

    float* sbuf = (float*)d_ws;                       // 1024*36*128 f32
    float* xgcn = sbuf + (size_t)1024 * 36 * 128;     // 1024*36*128 f32
    short* wb   = (short*)(xgcn + (size_t)1024 * 36 * 128);
    short* ipwb = wb;                  // 2*384*128
    short* opwb = wb + 98304;          // 2*128*128
    short* fw1b = wb + 131072;         // 2*2048*128
    short* fw2p = wb + 655360;         // 2*128*2048 (permuted)

    cvt_all<<<1152, 256, 0, stream>>>(ipw, opw, fw1, fw2, wb);
    gcn_all<<<18433, 256, 0, stream>>>(x, Wg1, bg1, Wg2, bg2, xgcn);
    conv_branch<<<1024, 256, 0, stream>>>(x, c1w, c1b, c2w, c2b,
                                          bng, bnb, bnm, bnv, sbuf);
    for (int i = 0; i < 2; ++i) {
        attn_mfma<<<1024, 256, 0, stream>>>(sbuf,
            ipwb + (size_t)i * 49152, ipb + (size_t)i * 384,
            opwb + (size_t)i * 16384, opb + (size_t)i * 128,
            l1g + (size_t)i * 128, l1b + (size_t)i * 128);
        ffn_v5<<<576, 256, 0, stream>>>(sbuf,
            fw1b + (size_t)i * 262144, fb1 + (size_t)i * 2048,
            fw2p + (size_t)i * 262144, fb2 + (size_t)i * 128,
            l2g + (size_t)i * 128, l2b + (size_t)i * 128);
    }
    pool_head<<<1024, 128, 0, stream>>>(sbuf, xgcn, aww, awb, fcw, fcb, out);
}

// Round 11
// 334.977 us; speedup vs baseline: 1.2461x; 1.0061x over previous
//
#include <hip/hip_runtime.h>
#include <math.h>

#define EPSV   1e-5f

typedef __attribute__((ext_vector_type(8))) short bf16x8;
typedef __attribute__((ext_vector_type(4))) float f32x4;

__device__ __forceinline__ short f2bf(float f){
    unsigned u = __float_as_uint(f);
    u += 0x7fffu + ((u >> 16) & 1u);
    return (short)(u >> 16);
}
__device__ __forceinline__ f32x4 mfma16(bf16x8 a, bf16x8 b, f32x4 c){
    return __builtin_amdgcn_mfma_f32_16x16x32_bf16(a, b, c, 0, 0, 0);
}
__device__ __forceinline__ bf16x8 ldfrag(const short* base, int row, int kbyte, int rowBytes){
    int byte = row * rowBytes + kbyte;
    byte ^= (row & 7) << 4;
    return *(const bf16x8*)((const char*)base + byte);
}
__device__ __forceinline__ bf16x8 ldfragG(const short* base, int row, int kbyte, int rowBytes){
    return *(const bf16x8*)((const char*)base + (size_t)row * rowBytes + kbyte);
}
__device__ __forceinline__ void stswz(short* base, int row, int col, int rowBytes, short v){
    int byte = row * rowBytes + col * 2;
    byte ^= (row & 7) << 4;
    *(short*)((char*)base + byte) = v;
}

// ---------------------------------------------------------------------------
// one-shot fp32 -> bf16 weight conversion (unchanged).
// fw2p: fw2p[(((grp*128 + c)*4 + lg)*8 + s)] = W2[c][grp*32 + (s>>2)*16 + lg*4 + (s&3)]
// ---------------------------------------------------------------------------
__global__ __launch_bounds__(256) void cvt_all(
    const float* __restrict__ ipw, const float* __restrict__ opw,
    const float* __restrict__ fw1, const float* __restrict__ fw2,
    short* __restrict__ dst)
{
    int i = (blockIdx.x * 256 + threadIdx.x) * 4;
    if (i >= 1179648) return;
    const float* src; int off;
    if (i < 98304)       { src = ipw; off = i; }
    else if (i < 131072) { src = opw; off = i - 98304; }
    else if (i < 655360) { src = fw1; off = i - 131072; }
    else {
        int o  = i - 655360;
        int L  = o >> 18;
        int oo = o & 262143;
        int s0 = oo & 7;
        int lg = (oo >> 3) & 3;
        int c  = (oo >> 5) & 127;
        int grp = oo >> 12;
        int n  = grp * 32 + ((s0 >> 2) << 4) + lg * 4;
        src = fw2; off = L * 262144 + c * 2048 + n;
        float4 v = *(const float4*)(src + off);
        short4 s;
        s.x = f2bf(v.x); s.y = f2bf(v.y); s.z = f2bf(v.z); s.w = f2bf(v.w);
        *(short4*)(dst + i) = s;
        return;
    }
    float4 v = *(const float4*)(src + off);
    short4 s;
    s.x = f2bf(v.x); s.y = f2bf(v.y); s.z = f2bf(v.z); s.w = f2bf(v.w);
    *(short4*)(dst + i) = s;
}

// ---------------------------------------------------------------------------
// GCN branch (unchanged)
// ---------------------------------------------------------------------------
__global__ __launch_bounds__(256) void gcn_all(
    const float* __restrict__ x,
    const float* __restrict__ Wg1, const float* __restrict__ bg1,
    const float* __restrict__ Wg2, const float* __restrict__ bg2,
    float* __restrict__ xgcn)
{
    int tid = threadIdx.x;
    if (blockIdx.x == 18432) {
        __shared__ float xgm[9];
        __shared__ float h1s[64];
        if (tid < 9) {
            float s = 0.f;
            for (int r = 0; r < 9; ++r) {
                const float* xp = x + (r * 9 + tid) * 7;
                #pragma unroll
                for (int f = 0; f < 7; ++f) s += xp[f];
            }
            xgm[tid] = s * (1.f / 63.f);
        }
        __syncthreads();
        if (tid < 64) {
            float acc = bg1[tid];
            #pragma unroll
            for (int j = 0; j < 9; ++j) acc += xgm[j] * Wg1[j * 64 + tid];
            h1s[tid] = fmaxf(acc, 0.f);
        }
        __syncthreads();
        if (tid < 128) {
            float acc = bg2[tid];
            #pragma unroll 8
            for (int c = 0; c < 64; ++c) acc += h1s[c] * Wg2[c * 128 + tid];
            float v = fmaxf(acc, 0.f);
            for (int r = 0; r < 9; ++r) xgcn[r * 128 + tid] = v;
        }
        return;
    }

    __shared__ float xg[2][9];
    __shared__ float h1[2][64];
    int ri = tid >> 7;
    int tr = tid & 127;
    int row = blockIdx.x * 2 + ri;

    if (tr < 9) {
        const float* xp = x + (row * 9 + tr) * 7;
        float s = 0.f;
        #pragma unroll
        for (int f = 0; f < 7; ++f) s += xp[f];
        xg[ri][tr] = s * (1.f / 7.f);
    }
    __syncthreads();
    if (tr < 64) {
        float acc = bg1[tr];
        #pragma unroll
        for (int j = 0; j < 9; ++j) acc += xg[ri][j] * Wg1[j * 64 + tr];
        h1[ri][tr] = fmaxf(acc, 0.f);
    }
    __syncthreads();
    if (row >= 9) {
        float acc = bg2[tr];
        #pragma unroll 8
        for (int c = 0; c < 64; ++c) acc += h1[ri][c] * Wg2[c * 128 + tr];
        xgcn[row * 128 + tr] = fmaxf(acc, 0.f);
    }
}

// ---------------------------------------------------------------------------
// Conv branch (unchanged)
// ---------------------------------------------------------------------------
__global__ __launch_bounds__(256) void conv_branch(
    const float* __restrict__ x,
    const float* __restrict__ w1, const float* __restrict__ cb1,
    const float* __restrict__ w2, const float* __restrict__ cb2,
    const float* __restrict__ bng, const float* __restrict__ bnb,
    const float* __restrict__ bnm, const float* __restrict__ bnv,
    float* __restrict__ sbuf)
{
    __shared__ float xm[7 * 40];
    __shared__ float w1s[64 * 35];
    __shared__ float o1[64 * 38];
    int tid = threadIdx.x;
    int b = blockIdx.x;

    for (int idx = tid; idx < 7 * 40; idx += 256) xm[idx] = 0.f;
    for (int idx = tid; idx < 64 * 38; idx += 256) o1[idx] = 0.f;
    for (int idx = tid; idx < 2240; idx += 256) w1s[idx] = w1[idx];
    __syncthreads();

    const float* xb = x + (size_t)b * 2268;
    for (int idx = tid; idx < 252; idx += 256) {
        int f = idx / 36, l = idx - f * 36;
        float s = 0.f;
        #pragma unroll
        for (int n = 0; n < 9; ++n) s += xb[n * 252 + idx];
        xm[f * 40 + l + 2] = s * (1.f / 9.f);
    }
    __syncthreads();

    {
        int o = tid & 63, lh = tid >> 6;
        int l0 = lh * 9;
        float acc[9];
        float bias = cb1[o];
        #pragma unroll
        for (int r = 0; r < 9; ++r) acc[r] = bias;
        #pragma unroll
        for (int i = 0; i < 7; ++i) {
            #pragma unroll
            for (int k = 0; k < 5; ++k) {
                float w = w1s[o * 35 + i * 5 + k];
                const float* xrow = &xm[i * 40 + l0 + k];
                #pragma unroll
                for (int r = 0; r < 9; ++r) acc[r] += w * xrow[r];
            }
        }
        #pragma unroll
        for (int r = 0; r < 9; ++r) o1[o * 38 + l0 + r + 1] = acc[r];
    }
    __syncthreads();

    {
        int c = tid & 127, lh = tid >> 7;
        int l0 = lh * 18;
        float acc[18];
        #pragma unroll
        for (int r = 0; r < 18; ++r) acc[r] = 0.f;
        const float* w2c = w2 + c * 192;
        for (int i = 0; i < 64; ++i) {
            float wa = w2c[i * 3 + 0], wb = w2c[i * 3 + 1], wc = w2c[i * 3 + 2];
            const float* orow = &o1[i * 38 + l0];
            #pragma unroll
            for (int r = 0; r < 18; ++r)
                acc[r] += wa * orow[r] + wb * orow[r + 1] + wc * orow[r + 2];
        }
        float scale = bng[c] * rsqrtf(bnv[c] + EPSV);
        float shift = bnb[c] - bnm[c] * scale;
        float bias  = cb2[c];
        float* sb = sbuf + ((size_t)b * 36 + l0) * 128 + c;
        #pragma unroll
        for (int r = 0; r < 18; ++r)
            sb[r * 128] = (acc[r] + bias) * scale + shift;
    }
}

// ---------------------------------------------------------------------------
// Attention + out-proj + residual + LN1.
// LDS arena trimmed to 46208 B -> 3 blocks/CU. Pad-row READS poke adjacent
// buffers (A-operand-row garbage -> outputs discarded); pad-row WRITES are
// guarded (r<36). Contraction dims stay zeroed: Vt cols 36..63, Pb cols 36..63.
// ---------------------------------------------------------------------------
__global__ __launch_bounds__(256, 3) void attn_mfma(
    float* __restrict__ sbuf,
    const short* __restrict__ ipwb, const float* __restrict__ ipb,
    const short* __restrict__ opwb, const float* __restrict__ opb,
    const float* __restrict__ l1g, const float* __restrict__ l1b)
{
    __shared__ char AR[46208] __attribute__((aligned(16)));
    short* Sb = (short*)(AR);          // 36x128 bf16 swz (alloc 9216)
    short* Qb = (short*)(AR + 9216);   // 36x64  (alloc 4608)
    short* Kb = (short*)(AR + 13824);  // 36x64  (alloc 4608)
    short* Vt = (short*)(AR + 18432);  // 64x64 [d][seq] (alloc 8192)
    short* Pb = (short*)(AR + 26624);  // 36x64  (alloc 4608)
    short* Hb = (short*)(AR + 31232);  // 36x128 (alloc 9216)
    float* scf = (float*)(AR + 40448); // 36x40  (alloc 5760)

    const int tid  = threadIdx.x;
    const int wid  = tid >> 6;
    const int lane = tid & 63;
    const int lr   = lane & 15;
    const int lg   = lane >> 4;
    const int kbse = lg * 16;

    float* sg = sbuf + (size_t)blockIdx.x * 4608;
    const f32x4 fzero = {0.f, 0.f, 0.f, 0.f};

    for (int idx = tid; idx < 4608; idx += 256) {
        int r = idx >> 7, c = idx & 127;
        stswz(Sb, r, c, 256, f2bf(sg[idx]));
    }
    for (int idx = tid; idx < 1024; idx += 256)   // Vt seq 48..63 (contraction pad)
        stswz(Vt, idx >> 4, 48 + (idx & 15), 128, 0);
    __syncthreads();

    for (int h = 0; h < 2; ++h) {
        {   // q,k,v projections
            f32x4 acc[3][3];
            #pragma unroll
            for (int a = 0; a < 3; ++a)
                #pragma unroll
                for (int m = 0; m < 3; ++m) acc[a][m] = fzero;
            const int wrow0 = h * 64 + wid * 16 + lr;
            #pragma unroll
            for (int ks = 0; ks < 4; ++ks) {
                bf16x8 a0 = ldfrag(Sb,      lr, ks * 64 + kbse, 256);
                bf16x8 a1 = ldfrag(Sb, 16 + lr, ks * 64 + kbse, 256);
                bf16x8 a2 = ldfrag(Sb, 32 + lr, ks * 64 + kbse, 256);
                #pragma unroll
                for (int mat = 0; mat < 3; ++mat) {
                    bf16x8 bf = ldfragG(ipwb, mat * 128 + wrow0, ks * 64 + kbse, 256);
                    acc[mat][0] = mfma16(a0, bf, acc[mat][0]);
                    acc[mat][1] = mfma16(a1, bf, acc[mat][1]);
                    acc[mat][2] = mfma16(a2, bf, acc[mat][2]);
                }
            }
            int col = wid * 16 + lr;
            #pragma unroll
            for (int mat = 0; mat < 3; ++mat) {
                float bias = ipb[mat * 128 + h * 64 + col];
                #pragma unroll
                for (int mt = 0; mt < 3; ++mt) {
                    f32x4 c4 = acc[mat][mt];
                    if (mat == 0) {
                        #pragma unroll
                        for (int j = 0; j < 4; ++j) {
                            int r = mt * 16 + lg * 4 + j;
                            if (r < 36) stswz(Qb, r, col, 128, f2bf(c4[j] + bias));
                        }
                    } else if (mat == 1) {
                        #pragma unroll
                        for (int j = 0; j < 4; ++j) {
                            int r = mt * 16 + lg * 4 + j;
                            if (r < 36) stswz(Kb, r, col, 128, f2bf(c4[j] + bias));
                        }
                    } else {
                        // Vt[d=col][seq]; seq>=36 forced to 0 (PV contraction dim)
                        int rbase = mt * 16 + lg * 4;
                        short4 s4;
                        s4.x = f2bf(rbase + 0 < 36 ? c4[0] + bias : 0.f);
                        s4.y = f2bf(rbase + 1 < 36 ? c4[1] + bias : 0.f);
                        s4.z = f2bf(rbase + 2 < 36 ? c4[2] + bias : 0.f);
                        s4.w = f2bf(rbase + 3 < 36 ? c4[3] + bias : 0.f);
                        int byte = col * 128 + rbase * 2;
                        byte ^= (col & 7) << 4;
                        *(short4*)((char*)Vt + byte) = s4;
                    }
                }
            }
        }
        __syncthreads();

        // scores
        for (int t = wid; t < 9; t += 4) {
            int mt = t / 3, nt = t - mt * 3;
            f32x4 acc = fzero;
            #pragma unroll
            for (int ks = 0; ks < 2; ++ks) {
                bf16x8 a = ldfrag(Qb, mt * 16 + lr, ks * 64 + kbse, 128);
                bf16x8 b = ldfrag(Kb, nt * 16 + lr, ks * 64 + kbse, 128);
                acc = mfma16(a, b, acc);
            }
            int col = nt * 16 + lr;
            if (col < 36) {
                #pragma unroll
                for (int j = 0; j < 4; ++j) {
                    int r = mt * 16 + lg * 4 + j;
                    if (r < 36) scf[r * 40 + col] = acc[j] * 0.125f;
                }
            }
        }
        __syncthreads();

        // softmax (4 lanes per row); writes cols 0..63 of Pb (36..63 zero)
        {
            int g = tid >> 2, e = tid & 3;
            if (g < 36) {
                float v[9];
                float mx = -1e30f;
                #pragma unroll
                for (int i = 0; i < 9; ++i) { v[i] = scf[g * 40 + e * 9 + i]; mx = fmaxf(mx, v[i]); }
                mx = fmaxf(mx, __shfl_xor(mx, 1));
                mx = fmaxf(mx, __shfl_xor(mx, 2));
                float ssum = 0.f;
                #pragma unroll
                for (int i = 0; i < 9; ++i) { v[i] = __expf(v[i] - mx); ssum += v[i]; }
                ssum += __shfl_xor(ssum, 1);
                ssum += __shfl_xor(ssum, 2);
                float inv = 1.f / ssum;
                #pragma unroll
                for (int i = 0; i < 9; ++i)
                    stswz(Pb, g, e * 9 + i, 128, f2bf(v[i] * inv));
                #pragma unroll
                for (int i = 0; i < 7; ++i)
                    stswz(Pb, g, 36 + e * 7 + i, 128, 0);
            }
        }
        __syncthreads();

        // o = P @ V
        {
            f32x4 oacc[3] = {fzero, fzero, fzero};
            #pragma unroll
            for (int ks = 0; ks < 2; ++ks) {
                bf16x8 b = ldfrag(Vt, wid * 16 + lr, ks * 64 + kbse, 128);
                #pragma unroll
                for (int mt = 0; mt < 3; ++mt) {
                    bf16x8 a = ldfrag(Pb, mt * 16 + lr, ks * 64 + kbse, 128);
                    oacc[mt] = mfma16(a, b, oacc[mt]);
                }
            }
            int col = h * 64 + wid * 16 + lr;
            #pragma unroll
            for (int mt = 0; mt < 3; ++mt)
                #pragma unroll
                for (int j = 0; j < 4; ++j) {
                    int r = mt * 16 + lg * 4 + j;
                    if (r < 36) stswz(Hb, r, col, 256, f2bf(oacc[mt][j]));
                }
        }
        __syncthreads();
    }

    // out-proj + residual + in-register LN1
    float z[3][2][4];
    {
        f32x4 pacc[3][2];
        #pragma unroll
        for (int m = 0; m < 3; ++m) { pacc[m][0] = fzero; pacc[m][1] = fzero; }
        #pragma unroll
        for (int ks = 0; ks < 4; ++ks) {
            bf16x8 a0 = ldfrag(Hb,      lr, ks * 64 + kbse, 256);
            bf16x8 a1 = ldfrag(Hb, 16 + lr, ks * 64 + kbse, 256);
            bf16x8 a2 = ldfrag(Hb, 32 + lr, ks * 64 + kbse, 256);
            #pragma unroll
            for (int t = 0; t < 2; ++t) {
                bf16x8 b = ldfragG(opwb, (wid * 2 + t) * 16 + lr, ks * 64 + kbse, 256);
                pacc[0][t] = mfma16(a0, b, pacc[0][t]);
                pacc[1][t] = mfma16(a1, b, pacc[1][t]);
                pacc[2][t] = mfma16(a2, b, pacc[2][t]);
            }
        }
        #pragma unroll
        for (int t = 0; t < 2; ++t) {
            int col = (wid * 2 + t) * 16 + lr;
            float bias = opb[col];
            #pragma unroll
            for (int mt = 0; mt < 3; ++mt)
                #pragma unroll
                for (int j = 0; j < 4; ++j) {
                    int r = mt * 16 + lg * 4 + j;
                    z[mt][t][j] = (r < 36) ? pacc[mt][t][j] + bias + sg[r * 128 + col] : 0.f;
                }
        }
    }
    {
        float* part = scf;
        #pragma unroll
        for (int mt = 0; mt < 3; ++mt)
            #pragma unroll
            for (int j = 0; j < 4; ++j) {
                int r = mt * 16 + lg * 4 + j;
                float s  = z[mt][0][j] + z[mt][1][j];
                float ss = z[mt][0][j] * z[mt][0][j] + z[mt][1][j] * z[mt][1][j];
                s  += __shfl_xor(s, 1);  s  += __shfl_xor(s, 2);
                s  += __shfl_xor(s, 4);  s  += __shfl_xor(s, 8);
                ss += __shfl_xor(ss, 1); ss += __shfl_xor(ss, 2);
                ss += __shfl_xor(ss, 4); ss += __shfl_xor(ss, 8);
                if (lr == 0 && r < 36) { part[r * 8 + wid] = s; part[r * 8 + 4 + wid] = ss; }
            }
    }
    __syncthreads();
    {
        const float* part = scf;
        #pragma unroll
        for (int mt = 0; mt < 3; ++mt)
            #pragma unroll
            for (int j = 0; j < 4; ++j) {
                int r = mt * 16 + lg * 4 + j;
                if (r < 36) {
                    float s  = part[r * 8 + 0] + part[r * 8 + 1] + part[r * 8 + 2] + part[r * 8 + 3];
                    float ss = part[r * 8 + 4] + part[r * 8 + 5] + part[r * 8 + 6] + part[r * 8 + 7];
                    float mean = s * (1.f / 128.f);
                    float rstd = rsqrtf(ss * (1.f / 128.f) - mean * mean + EPSV);
                    #pragma unroll
                    for (int t = 0; t < 2; ++t) {
                        int col = (wid * 2 + t) * 16 + lr;
                        float v = (z[mt][t][j] - mean) * rstd * l1g[col] + l1b[col];
                        sg[r * 128 + col] = v;
                    }
                }
            }
    }
}

// ---------------------------------------------------------------------------
// FFN v5b: round-10 structure + W2 XOR swizzle (kills the 8-way conflict on
// FFN2 ds_read_b128). 4 waves x 16 rows, chunk=32 neurons, 32KB LDS,
// 4 blocks/CU, 1 barrier/chunk, static indexing.
// ---------------------------------------------------------------------------
__global__ __launch_bounds__(256, 4) void ffn_v5(
    float* __restrict__ sres,
    const short* __restrict__ fw1b, const float* __restrict__ fb1,
    const short* __restrict__ fw2p, const float* __restrict__ fb2,
    const float* __restrict__ l2g, const float* __restrict__ l2b)
{
    __shared__ short Wbuf[2][8192] __attribute__((aligned(16)));   // 32 KB

    const int tid  = threadIdx.x;
    const int wid  = tid >> 6;
    const int lane = tid & 63;
    const int lr   = lane & 15;
    const int lg   = lane >> 4;
    const size_t row0 = (size_t)blockIdx.x * 64 + wid * 16;
    const f32x4 fzero = {0.f, 0.f, 0.f, 0.f};

    // persistent S fragments (B-operand of swapped FFN1)
    bf16x8 sfrag[4];
    {
        const float* sp = sres + (row0 + lr) * 128;
        #pragma unroll
        for (int ks = 0; ks < 4; ++ks) {
            float4 lo = *(const float4*)(sp + ks * 32 + lg * 8);
            float4 hi = *(const float4*)(sp + ks * 32 + lg * 8 + 4);
            bf16x8 f;
            f[0] = f2bf(lo.x); f[1] = f2bf(lo.y); f[2] = f2bf(lo.z); f[3] = f2bf(lo.w);
            f[4] = f2bf(hi.x); f[5] = f2bf(hi.y); f[6] = f2bf(hi.z); f[7] = f2bf(hi.w);
            sfrag[ks] = f;
        }
    }

    f32x4 facc[8];
    #pragma unroll
    for (int ct = 0; ct < 8; ++ct) facc[ct] = fzero;

    // staging: per chunk 16KB total -> 2x16B W1 + 2x16B W2 per thread.
    // W1 swizzled by row; W2 swizzled by byte^=((byte>>7)&3)<<4.
    bf16x8 g1[2], g2[2];
    #pragma unroll
    for (int i = 0; i < 2; ++i) {
        int fid = tid + 256 * i;
        g1[i] = *(const bf16x8*)((const char*)fw1b + fid * 16);
        g2[i] = *(const bf16x8*)((const char*)fw2p + fid * 16);
    }
    #pragma unroll
    for (int i = 0; i < 2; ++i) {
        int fid = tid + 256 * i;
        int b1 = fid * 16;
        int s1 = b1 ^ (((b1 >> 8) & 7) << 4);     // row = b1>>8 (256B rows)
        int s2 = b1 ^ (((b1 >> 7) & 3) << 4);
        *(bf16x8*)((char*)&Wbuf[0][0] + s1)    = g1[i];
        *(bf16x8*)((char*)&Wbuf[0][4096] + s2) = g2[i];
    }

#define FFN_CHUNK(Q, CUR, NXT)                                                    \
    {                                                                             \
        const int q = (Q);                                                        \
        if (q < 63) {                                                             \
            const char* b1p = (const char*)fw1b + (q + 1) * 8192;                 \
            const char* b2p = (const char*)fw2p + (q + 1) * 8192;                 \
            _Pragma("unroll")                                                     \
            for (int i = 0; i < 2; ++i) {                                         \
                int fid = tid + 256 * i;                                          \
                g1[i] = *(const bf16x8*)(b1p + fid * 16);                         \
                g2[i] = *(const bf16x8*)(b2p + fid * 16);                         \
            }                                                                     \
        }                                                                         \
        __syncthreads();  /* buf[CUR] writes (prev iter) visible */               \
        const short* W1l = &Wbuf[CUR][0];                                         \
        const short* W2l = &Wbuf[CUR][4096];                                      \
        /* FFN1 swapped: A = W1 frag (LDS), B = sfrag -> H^T in regs */           \
        f32x4 hacc[2];                                                            \
        hacc[0] = fzero; hacc[1] = fzero;                                         \
        _Pragma("unroll")                                                         \
        for (int ks = 0; ks < 4; ++ks) {                                          \
            bf16x8 a0 = ldfrag(W1l,      lr, ks * 64 + lg * 16, 256);             \
            bf16x8 a1 = ldfrag(W1l, 16 + lr, ks * 64 + lg * 16, 256);             \
            hacc[0] = mfma16(a0, sfrag[ks], hacc[0]);                             \
            hacc[1] = mfma16(a1, sfrag[ks], hacc[1]);                             \
        }                                                                         \
        /* bias + relu + pack: slot s <-> n = (s>>2)*16 + lg*4 + (s&3) */         \
        float4 bA = *(const float4*)(fb1 + q * 32 + lg * 4);                      \
        float4 bB = *(const float4*)(fb1 + q * 32 + 16 + lg * 4);                 \
        bf16x8 hf;                                                                \
        hf[0] = f2bf(fmaxf(hacc[0][0] + bA.x, 0.f));                              \
        hf[1] = f2bf(fmaxf(hacc[0][1] + bA.y, 0.f));                              \
        hf[2] = f2bf(fmaxf(hacc[0][2] + bA.z, 0.f));                              \
        hf[3] = f2bf(fmaxf(hacc[0][3] + bA.w, 0.f));                              \
        hf[4] = f2bf(fmaxf(hacc[1][0] + bB.x, 0.f));                              \
        hf[5] = f2bf(fmaxf(hacc[1][1] + bB.y, 0.f));                              \
        hf[6] = f2bf(fmaxf(hacc[1][2] + bB.z, 0.f));                              \
        hf[7] = f2bf(fmaxf(hacc[1][3] + bB.w, 0.f));                              \
        /* FFN2: A = hf (regs), B = W2 frag (LDS, swizzled -> 2-way max) */       \
        _Pragma("unroll")                                                         \
        for (int ct = 0; ct < 8; ++ct) {                                          \
            int wb2 = ((ct * 16 + lr) * 4 + lg) * 16;                             \
            wb2 ^= ((lr >> 1) & 3) << 4;                                          \
            bf16x8 b2f = *(const bf16x8*)((const char*)W2l + wb2);                \
            facc[ct] = mfma16(hf, b2f, facc[ct]);                                 \
        }                                                                         \
        if (q < 63) {                                                             \
            char* d1 = (char*)&Wbuf[NXT][0];                                      \
            char* d2 = (char*)&Wbuf[NXT][4096];                                   \
            _Pragma("unroll")                                                     \
            for (int i = 0; i < 2; ++i) {                                         \
                int fid = tid + 256 * i;                                          \
                int b1 = fid * 16;                                                \
                int s1 = b1 ^ (((b1 >> 8) & 7) << 4);                             \
                int s2 = b1 ^ (((b1 >> 7) & 3) << 4);                             \
                *(bf16x8*)(d1 + s1) = g1[i];                                      \
                *(bf16x8*)(d2 + s2) = g2[i];                                      \
            }                                                                     \
        }                                                                         \
    }

    #pragma unroll 1
    for (int qq = 0; qq < 32; ++qq) {
        FFN_CHUNK(2 * qq,     0, 1)
        FFN_CHUNK(2 * qq + 1, 1, 0)
    }
#undef FFN_CHUNK

    // epilogue: + b2 + residual, in-wave LN2, write back
    float zv[8][4];
    #pragma unroll
    for (int ct = 0; ct < 8; ++ct) {
        int c = ct * 16 + lr;
        float b2v = fb2[c];
        #pragma unroll
        for (int j = 0; j < 4; ++j)
            zv[ct][j] = facc[ct][j] + b2v + sres[(row0 + lg * 4 + j) * 128 + c];
    }
    #pragma unroll
    for (int j = 0; j < 4; ++j) {
        float s = 0.f, sq = 0.f;
        #pragma unroll
        for (int ct = 0; ct < 8; ++ct) { s += zv[ct][j]; sq += zv[ct][j] * zv[ct][j]; }
        s  += __shfl_xor(s, 1);  s  += __shfl_xor(s, 2);
        s  += __shfl_xor(s, 4);  s  += __shfl_xor(s, 8);
        sq += __shfl_xor(sq, 1); sq += __shfl_xor(sq, 2);
        sq += __shfl_xor(sq, 4); sq += __shfl_xor(sq, 8);
        float mean = s * (1.f / 128.f);
        float rstd = rsqrtf(sq * (1.f / 128.f) - mean * mean + EPSV);
        float* og = sres + (row0 + lg * 4 + j) * 128;
        #pragma unroll
        for (int ct = 0; ct < 8; ++ct) {
            int c = ct * 16 + lr;
            og[c] = (zv[ct][j] - mean) * rstd * l2g[c] + l2b[c];
        }
    }
}

// ---------------------------------------------------------------------------
// pool + head (unchanged)
// ---------------------------------------------------------------------------
__global__ __launch_bounds__(128) void pool_head(
    const float* __restrict__ sbuf, const float* __restrict__ xgcn,
    const float* __restrict__ aww, const float* __restrict__ awb,
    const float* __restrict__ fcw, const float* __restrict__ fcb,
    float* __restrict__ out)
{
    __shared__ float sl[36][128];
    __shared__ float zz[36];
    __shared__ float p[128];
    int tid = threadIdx.x;
    int b = blockIdx.x;
    const float* sg = sbuf + (size_t)b * 4608;
    const float* gg = xgcn + (size_t)b * 4608;
    for (int idx = tid; idx < 4608; idx += 128)
        sl[0][idx] = sg[idx] + gg[idx];
    __syncthreads();
    if (tid < 36) {
        float acc = awb[0];
        #pragma unroll
        for (int j = 0; j < 128; j += 4) {
            float4 s4 = *(const float4*)&sl[tid][j];
            float4 w4 = *(const float4*)(aww + j);
            acc += s4.x * w4.x + s4.y * w4.y + s4.z * w4.z + s4.w * w4.w;
        }
        zz[tid] = acc;
    }
    __syncthreads();
    if (tid == 0) {
        float m = -1e30f;
        for (int k = 0; k < 36; ++k) m = fmaxf(m, zz[k]);
        float ssum = 0.f;
        for (int k = 0; k < 36; ++k) ssum += __expf(zz[k] - m);
        float inv = 1.f / ssum;
        for (int k = 0; k < 36; ++k) zz[k] = __expf(zz[k] - m) * inv;
    }
    __syncthreads();
    {
        float acc = 0.f;
        for (int l = 0; l < 36; ++l) acc += sl[l][tid] * zz[l];
        p[tid] = acc;
    }
    __syncthreads();
    if (tid == 0) {
        float acc = fcb[0];
        for (int dd = 0; dd < 128; ++dd) acc += p[dd] * fcw[dd];
        out[b] = acc >= 0.f ? acc : 0.1f * acc;
    }
}

// ---------------------------------------------------------------------------
extern "C" void kernel_launch(void* const* d_in, const int* in_sizes, int n_in,
                              void* d_out, int out_size, void* d_ws, size_t ws_size,
                              hipStream_t stream)
{
    const float* x   = (const float*)d_in[0];
    const float* Wg1 = (const float*)d_in[1];
    const float* bg1 = (const float*)d_in[2];
    const float* Wg2 = (const float*)d_in[3];
    const float* bg2 = (const float*)d_in[4];
    const float* c1w = (const float*)d_in[5];
    const float* c1b = (const float*)d_in[6];
    const float* c2w = (const float*)d_in[7];
    const float* c2b = (const float*)d_in[8];
    const float* bng = (const float*)d_in[9];
    const float* bnb = (const float*)d_in[10];
    const float* bnm = (const float*)d_in[11];
    const float* bnv = (const float*)d_in[12];
    const float* ipw = (const float*)d_in[13];
    const float* ipb = (const float*)d_in[14];
    const float* opw = (const float*)d_in[15];
    const float* opb = (const float*)d_in[16];
    const float* l1g = (const float*)d_in[17];
    const float* l1b = (const float*)d_in[18];
    const float* l2g = (const float*)d_in[19];
    const float* l2b = (const float*)d_in[20];
    const float* fw1 = (const float*)d_in[21];
    const float* fb1 = (const float*)d_in[22];
    const float* fw2 = (const float*)d_in[23];
    const float* fb2 = (const float*)d_in[24];
    const float* aww = (const float*)d_in[25];
    const float* awb = (const float*)d_in[26];
    const float* fcw = (const float*)d_in[27];
    const float* fcb = (const float*)d_in[28];
    float* out = (float*)d_out;

    float* sbuf = (float*)d_ws;                       // 1024*36*128 f32
    float* xgcn = sbuf + (size_t)1024 * 36 * 128;     // 1024*36*128 f32
    short* wb   = (short*)(xgcn + (size_t)1024 * 36 * 128);
    short* ipwb = wb;                  // 2*384*128
    short* opwb = wb + 98304;          // 2*128*128
    short* fw1b = wb + 131072;         // 2*2048*128
    short* fw2p = wb + 655360;         // 2*128*2048 (permuted)

    cvt_all<<<1152, 256, 0, stream>>>(ipw, opw, fw1, fw2, wb);
    gcn_all<<<18433, 256, 0, stream>>>(x, Wg1, bg1, Wg2, bg2, xgcn);
    conv_branch<<<1024, 256, 0, stream>>>(x, c1w, c1b, c2w, c2b,
                                          bng, bnb, bnm, bnv, sbuf);
    for (int i = 0; i < 2; ++i) {
        attn_mfma<<<1024, 256, 0, stream>>>(sbuf,
            ipwb + (size_t)i * 49152, ipb + (size_t)i * 384,
            opwb + (size_t)i * 16384, opb + (size_t)i * 128,
            l1g + (size_t)i * 128, l1b + (size_t)i * 128);
        ffn_v5<<<576, 256, 0, stream>>>(sbuf,
            fw1b + (size_t)i * 262144, fb1 + (size_t)i * 2048,
            fw2p + (size_t)i * 262144, fb2 + (size_t)i * 128,
            l2g + (size_t)i * 128, l2b + (size_t)i * 128);
    }
    pool_head<<<1024, 128, 0, stream>>>(sbuf, xgcn, aww, awb, fcw, fcb, out);
}